// Round 13
// baseline (83.496 us; speedup 1.0000x reference)
//
#include <hip/hip_runtime.h>
#include <hip/hip_bf16.h>

#define SEQ   512
#define LPAD  64
#define RPAD  68
#define TOT   (SEQ + LPAD + RPAD)   // 644 float4 per sequence
#define C1f   14.426950408889634f    // 1/(gamma*ln2), gamma=0.1
#define K1f   0.069314718055994531f  // gamma*ln2
#define SATf  60.0f                  // exp2-arg saturation (no f32 inf)

#if __has_builtin(__builtin_amdgcn_exp2f)
#define EXP2(x) __builtin_amdgcn_exp2f(x)
#else
#define EXP2(x) exp2f(x)
#endif

#define SB() __builtin_amdgcn_sched_barrier(0)

__device__ __forceinline__ float cost4(float4 X, float4 Y) {
  return fabsf(X.x - Y.x) + fabsf(X.y - Y.y) + fabsf(X.z - Y.z) + fabsf(X.w - Y.w);
}

// f32 lane shifts via DPP wave shifts: 0-fill at edges (0 == exp-domain BIG).
__device__ __forceinline__ float fshr1(float x) {  // lane t <- lane t+1; lane63 <- 0
  return __int_as_float(__builtin_amdgcn_update_dpp(0, __float_as_int(x), 0x138, 0xF, 0xF, true));
}
__device__ __forceinline__ float fshl1(float x) {  // lane t <- lane t-1; lane0 <- 0
  return __int_as_float(__builtin_amdgcn_update_dpp(0, __float_as_int(x), 0x130, 0xF, 0xF, true));
}

// ---- 1 cell/lane, band u = t in [0,63]; f32 exp-domain DP; feed-forward ----
// ---- bumps from BROADCAST center costs (uniform LDS reads, no readlane) ----
// pair n covers diags p=2n+1 (odd) and p=2n+2 (even).
//   odd  cell: i = n+t-31, j = n-t+32; neighbors: diag=dA, left=dB, up=fshl1(dB)
//   even cell: i = n+t-30, j = n-t+32; neighbors: diag=dB, up=nA, left=fshr1(nA)
// Windows, pair m -> slot m&3:  X0 = x[m+t-31], Y0 = y[m+32-t] (per-lane);
//   XC = x[m], YC = y[m+1] (uniform broadcast; = lane31's X0/Y0).
//   X1 (= x[m+1+t-31]) is next slot's X0;  XC1 is next slot's XC.
// Scale algebra (stored = true * 2^Ktot):
//   k1 = trunc(C1*costC_odd) + bq,  k2 = trunc(C1*costC_even)
//   nA = PoS2*dA + Po*(dB+up),  Po = 2^(-cO*C1+k1), PoS2 = 2^(-cO*C1+k1+k2prev)
//   nB = PeS1*dB + Pe*(nA+lf),  Pe = 2^(-cE*C1+k2), PeS1 = 2^(-cE*C1+k2+k1)
#define DECLS(s) \
  float4 X0##s, Y0##s, XC##s, YC##s; \
  float Po##s, PoS2##s, Pe##s, PeS1##s, k2f##s;

#define LOADW(s, m) do { \
    X0##s = pX[(m)]; Y0##s = pY[(m)]; \
    XC##s = sxp[(m)]; YC##s = syp[(m) + 1]; } while (0)

// P factors for pair in slot s; sp = prev pair's slot (k2prev), sn = next
// pair's slot (supplies X1 = X0[m+1] and XC1 = XC[m+1]).
#define COMPP(s, sp, sn) do { \
    float _cO = cost4(X0##s, Y0##s); \
    float _cE = cost4(X0##sn, Y0##s); \
    float _c0 = cost4(XC##s, YC##s); \
    float _c1 = cost4(XC##sn, YC##s); \
    float _k1 = truncf(_c0 * C1f) + bqf; \
    float _k2 = truncf(_c1 * C1f); \
    Ktot += _k1 + _k2; \
    Po##s   = EXP2(fminf(fmaf(_cO, -C1f, _k1),           SATf)); \
    PoS2##s = EXP2(fminf(fmaf(_cO, -C1f, _k1 + k2f##sp), SATf)); \
    Pe##s   = EXP2(fminf(fmaf(_cE, -C1f, _k2),           SATf)); \
    PeS1##s = EXP2(fminf(fmaf(_cE, -C1f, _k2 + _k1),     SATf)); \
    k2f##s = _k2; } while (0)

// f32 recurrence for one pair (odd diag then even diag). ~6-op serial chain.
#define CHAIN(s) do { \
    float _up = fshl1(dB); \
    float _t1 = Po##s * (dB + _up); \
    float _nA = fmaf(PoS2##s, dA, _t1); \
    float _lf = fshr1(_nA); \
    float _t2 = Pe##s * (_nA + _lf); \
    float _nB = fmaf(PeS1##s, dB, _t2); \
    dA = _nA; dB = _nB; } while (0)

// lag-2 residual correction; center cell = lane31 even diag (always valid).
#define FEEDBACK() do { \
    int _hib = __builtin_amdgcn_readlane(__float_as_int(dB), 31); \
    int _e8 = (_hib >> 23) & 0xFF; \
    int _nb = (127 - _e8) - bq1; \
    _nb = _nb < -60 ? -60 : (_nb > 60 ? 60 : _nb); \
    bq1 = _nb; bqf = (float)bq1; } while (0)

// phase n: COMPP pair n+1 (slots n+1, prev n, next n+2), LOAD pair n+3,
// CHAIN pair n. Loads placed AFTER COMPP so the lgkmcnt wait before COMPP
// only covers loads >= 1 phase old (consumed values are 2 phases old).
#define PHASE(sC, sCp, sCn, sL, sP, m) do { \
    SB(); \
    COMPP(sC, sCp, sCn); \
    LOADW(sL, m); \
    CHAIN(sP); \
    FEEDBACK(); } while (0)

// Blocks 0..95: banded soft-DTW per extended batch element -> ws[b].
// Block 96: KL + transition-count losses -> ws[96..98]. Runs concurrently.
__global__ __launch_bounds__(256, 1) void sdtw_fused_kernel(
    const float* __restrict__ at,    // [32,512,4]
    const float* __restrict__ mu,    // [32,64]
    const float* __restrict__ lv,    // [32,64]
    const float* __restrict__ ptc,   // [32,1]
    const float* __restrict__ gt,    // [32,512,4]
    float* __restrict__ ws)          // [0..95]=v, [96]=klS, [97]=auxS, [98]=trS
{
  __shared__ float4 sx[TOT];
  __shared__ float4 sy[TOT];
  __shared__ float s_g[32], s_ps[32], s_kl[32];

  const int blk = blockIdx.x;
  const int t   = threadIdx.x;

  if (blk < 96) {
    const float* xs;
    const float* ys;
    if (blk < 32)      { xs = at + (size_t)blk        * SEQ * 4; ys = gt + (size_t)blk * SEQ * 4; }
    else if (blk < 64) { xs = at + (size_t)(blk - 32) * SEQ * 4; ys = xs; }
    else               { xs = gt + (size_t)(blk - 64) * SEQ * 4; ys = xs; }

    for (int i = t; i < LPAD; i += 256) {
      sx[i] = make_float4(0.f, 0.f, 0.f, 0.f);
      sy[i] = make_float4(0.f, 0.f, 0.f, 0.f);
    }
    for (int i = LPAD + SEQ + t; i < TOT; i += 256) {
      sx[i] = make_float4(0.f, 0.f, 0.f, 0.f);
      sy[i] = make_float4(0.f, 0.f, 0.f, 0.f);
    }
    for (int i = t; i < SEQ; i += 256) {
      sx[LPAD + i] = ((const float4*)xs)[i];
      sy[LPAD + i] = ((const float4*)ys)[i];
    }
    __syncthreads();
    if (t >= 64) return;   // single wave runs the wavefront; no more barriers

    const float4* sxp = sx + LPAD;
    const float4* syp = sy + LPAD;
    const float4* pX = sxp + (t - 31);   // pX[m] = x[m+t-31]
    const float4* pY = syp + (32 - t);   // pY[m] = y[m-t+32]

    // seed: diag 0 = (0,0) at lane31 (even diag of pair -1, k2_{-1} = 0)
    float a0 = -C1f * cost4(sxp[0], syp[0]);
    float n0 = floorf(a0);
    float e00 = EXP2(a0 - n0);           // in [1,2)
    float dA = 0.0f;
    float dB = (t == 31) ? e00 : 0.0f;
    float Ktot = -n0;                    // lane-uniform, < 2^24: exact in f32
    int bq1 = 0;
    float bqf = 0.0f;

    DECLS(0) DECLS(1) DECLS(2) DECLS(3)
    k2f3 = 0.0f;   // k2prev for pair 0 = pair -1's even bump = 0

    // prologue: windows for pairs 0,1,2; P for pair 0
    LOADW(0, 0);
    LOADW(1, 1);
    LOADW(2, 2);
    COMPP(0, 3, 1);

    // steady: phases 0..507 (pairs 0..507 chained), slot = pair & 3
    #pragma unroll 1
    for (int g = 0; g < 127; ++g) {
      const int n = 4 * g;
      PHASE(1, 0, 2, 3, 0, n + 3);   // phase n
      PHASE(2, 1, 3, 0, 1, n + 4);   // phase n+1
      PHASE(3, 2, 0, 1, 2, n + 5);   // phase n+2
      PHASE(0, 3, 1, 2, 3, n + 6);   // phase n+3
    }
    // tail: phases 508, 509, then final chain of pair 510
    SB(); COMPP(1, 0, 2); LOADW(3, 511); CHAIN(0); FEEDBACK();
    SB(); COMPP(2, 1, 3); CHAIN(1); FEEDBACK();
    SB(); CHAIN(2);

    if (t == 31) {
      // final cell (511,511) = even diag of pair 510, lane31
      // v = -gamma*ln(E_true) = -K1f*(log2(stored) - Ktot)
      int bits = __float_as_int(dB);
      int e8 = (bits >> 23) & 0xFF;
      float mant = __int_as_float((bits & 0x7FFFFF) | 0x3F800000);
      double l2 = (double)(e8 - 127) + (double)__log2f(mant);
      ws[blk] = (float)(-(double)K1f * (l2 - (double)Ktot));
    }
    return;
  }

  // ---------- loss block (blk == 96), 256 threads: 8 per batch element ----------
  const int b = t >> 3, seg = t & 7;

  float s = 0.f;
  {
    const float* mb = mu + b * 64 + seg * 8;
    const float* lb = lv + b * 64 + seg * 8;
    #pragma unroll
    for (int z = 0; z < 8; ++z) {
      float m = mb[z], l = lb[z];
      s += 1.0f + l - m * m - __expf(l);
    }
  }
  s += __shfl_down(s, 4, 8);
  s += __shfl_down(s, 2, 8);
  s += __shfl_down(s, 1, 8);

  float g = 0.f, ps = 0.f;
  {
    const int n0 = seg * 64;
    const int nstart = (seg == 0) ? 1 : n0;
    const float* gb = gt + (size_t)b * SEQ * 4 + 2;
    const float* ab = at + (size_t)b * SEQ * 4 + 2;
    float pg = gb[(nstart - 1) * 4];
    float pp = 1.0f / (1.0f + __expf((0.5f - ab[(nstart - 1) * 4]) * 10.0f));
    for (int n = nstart; n < n0 + 64; ++n) {
      float cg = gb[n * 4]; g += fabsf(cg - pg); pg = cg;
      float cp = 1.0f / (1.0f + __expf((0.5f - ab[n * 4]) * 10.0f));
      ps += fabsf(cp - pp); pp = cp;
    }
  }
  g  += __shfl_down(g, 4, 8);  g  += __shfl_down(g, 2, 8);  g  += __shfl_down(g, 1, 8);
  ps += __shfl_down(ps, 4, 8); ps += __shfl_down(ps, 2, 8); ps += __shfl_down(ps, 1, 8);

  if (seg == 0) {
    s_g[b]  = g;
    s_ps[b] = ps;
    s_kl[b] = fmaxf(-0.5f * s - 0.5f, 0.0f);
  }
  __syncthreads();

  if (t < 32) {
    float gv  = s_g[t];
    float kl  = s_kl[t];
    float d   = ptc[t] - gv;  float aux = d * d;
    float e   = s_ps[t] - gv; float tr  = e * e;
    kl  += __shfl_down(kl, 16, 32); aux += __shfl_down(aux, 16, 32); tr += __shfl_down(tr, 16, 32);
    kl  += __shfl_down(kl,  8, 32); aux += __shfl_down(aux,  8, 32); tr += __shfl_down(tr,  8, 32);
    kl  += __shfl_down(kl,  4, 32); aux += __shfl_down(aux,  4, 32); tr += __shfl_down(tr,  4, 32);
    kl  += __shfl_down(kl,  2, 32); aux += __shfl_down(aux,  2, 32); tr += __shfl_down(tr,  2, 32);
    kl  += __shfl_down(kl,  1, 32); aux += __shfl_down(aux,  1, 32); tr += __shfl_down(tr,  1, 32);
    if (t == 0) { ws[96] = kl; ws[97] = aux; ws[98] = tr; }
  }
}

__global__ __launch_bounds__(64) void sdtw_combine_kernel(
    const float* __restrict__ ws, float* __restrict__ out)
{
  const int t = threadIdx.x;
  float vn = 0.f;
  if (t < 32) vn = ws[t] - 0.5f * (ws[32 + t] + ws[64 + t]);
  vn += __shfl_down(vn, 16, 32);
  vn += __shfl_down(vn,  8, 32);
  vn += __shfl_down(vn,  4, 32);
  vn += __shfl_down(vn,  2, 32);
  vn += __shfl_down(vn,  1, 32);
  if (t == 0) {
    float recon = vn * (1.0f / 1024.0f);   // mean(diag(v)) = sum/1024
    float kl    = ws[96] * (1.0f / 32.0f);
    float aux   = ws[97] * (1.0f / 32.0f);
    float tr    = ws[98] * (1.0f / 32.0f);
    out[0] = recon + kl + 0.1f * aux + 0.5f * tr;
    out[1] = recon;
    out[2] = kl;
    out[3] = aux;
    out[4] = tr;
  }
}

extern "C" void kernel_launch(void* const* d_in, const int* in_sizes, int n_in,
                              void* d_out, int out_size, void* d_ws, size_t ws_size,
                              hipStream_t stream) {
  const float* at  = (const float*)d_in[0];
  const float* mu  = (const float*)d_in[1];
  const float* lv  = (const float*)d_in[2];
  const float* ptc = (const float*)d_in[3];
  const float* gt  = (const float*)d_in[4];
  float* ws  = (float*)d_ws;
  float* out = (float*)d_out;

  sdtw_fused_kernel<<<97, 256, 0, stream>>>(at, mu, lv, ptc, gt, ws);
  sdtw_combine_kernel<<<1, 64, 0, stream>>>(ws, out);
}

// Round 14
// 50.381 us; speedup vs baseline: 1.6573x; 1.6573x over previous
//
#include <hip/hip_runtime.h>
#include <hip/hip_bf16.h>

#define SEQ   512
#define LPAD  64
#define RPAD  68
#define TOT   (SEQ + LPAD + RPAD)   // 644 float4 per sequence
#define C1f   14.426950408889634f    // 1/(gamma*ln2), gamma=0.1
#define K1f   0.069314718055994531f  // gamma*ln2

#if __has_builtin(__builtin_amdgcn_exp2f)
#define EXP2(x) __builtin_amdgcn_exp2f(x)
#else
#define EXP2(x) exp2f(x)
#endif

#define SB() __builtin_amdgcn_sched_barrier(0)

__device__ __forceinline__ float cost4(float4 X, float4 Y) {
  return fabsf(X.x - Y.x) + fabsf(X.y - Y.y) + fabsf(X.z - Y.z) + fabsf(X.w - Y.w);
}

// f64 lane shifts via DPP wave shifts: VALU, 0-fill at edges (0 == exp-domain BIG).
__device__ __forceinline__ double dshr1(double x) {  // lane t <- lane t+1; lane63 <- 0
  int lo = __builtin_amdgcn_update_dpp(0, __double2loint(x), 0x138, 0xF, 0xF, true);
  int hi = __builtin_amdgcn_update_dpp(0, __double2hiint(x), 0x138, 0xF, 0xF, true);
  return __hiloint2double(hi, lo);
}
__device__ __forceinline__ double dshl1(double x) {  // lane t <- lane t-1; lane0 <- 0
  int lo = __builtin_amdgcn_update_dpp(0, __double2loint(x), 0x130, 0xF, 0xF, true);
  int hi = __builtin_amdgcn_update_dpp(0, __double2hiint(x), 0x130, 0xF, 0xF, true);
  return __hiloint2double(hi, lo);
}
__device__ __forceinline__ double pow2i(int k) {     // 2^k exactly, |k| <= ~500
  union { unsigned long long u; double d; } v;
  v.u = ((unsigned long long)(1023 + k)) << 52;
  return v.d;
}

// ---- 1 cell/lane, band u = t in [0,63]; f64 exp-domain DP (R11 algebra) ----
// pair n covers diags p=2n+1 (odd) and p=2n+2 (even).
//   odd  cell: i = n+t-31, j = n-t+32; neighbors: diag=dA, left=dB, up=dshl1(dB)
//   even cell: i = n+t-30, j = n-t+32; neighbors: diag=dB, up=nA, left=dshr1(nA)
// windows: X0 = x[n+t-31], X1 = x[n+t-30], Y0 = y[n-t+32]
// 6 rotating slots; pair m -> slot m%6. TWO pairs per SB scheduling region.
#define DECLS(s) \
  float4 X0##s, X1##s, Y0##s; \
  double Po##s, Pe##s; \
  int k1##s, k2##s;

#define LOADW(s, m) do { \
    X0##s = pX[(m)]; X1##s = pX[(m) + 1]; Y0##s = pY[(m)]; } while (0)

// P factors for the pair in slot s with scale bump folded into the exp2 arg.
#define COMPP(s, bump) do { \
    k1##s = (bump) >> 1; k2##s = (bump) - k1##s; \
    float _f1 = (float)k1##s, _f2 = (float)k2##s; \
    Po##s = (double)EXP2(fmaf(cost4(X0##s, Y0##s), -C1f, _f1)); \
    Pe##s = (double)EXP2(fmaf(cost4(X1##s, Y0##s), -C1f, _f2)); } while (0)

// f64 recurrence for one pair; sp = previous pair's slot (supplies k2prev).
#define CHAIN(s, sp) do { \
    double _s2p = pow2i(k2##sp), _s1c = pow2i(k1##s); \
    double _up = dshl1(dB); \
    double _nA = Po##s * fma(dA, _s2p, dB + _up); \
    double _lf = dshr1(_nA); \
    double _nB = Pe##s * fma(dB, _s1c, _nA + _lf); \
    dA = _nA; dB = _nB; } while (0)

// lag-queue residual renorm feedback, once per group (2 pairs).
// center cell = lane31 even diag (n+1,n+1), always valid.
#define FEEDBACK() do { \
    int _hib = __builtin_amdgcn_readlane(__double2hiint(dB), 31); \
    int _def = 1023 - ((_hib >> 20) & 0x7ff); \
    Ktot += bq0; \
    int _nb = _def - bq1; _nb = _nb < -250 ? -250 : (_nb > 250 ? 250 : _nb); \
    bq0 = bq1; bq1 = _nb; } while (0)

// group k (pairs 2k,2k+1 chained): A=slot(2k), B=A+1, C=A+2, D=A+3, E=A+4,
// F=A+5 (mod 6). F also = slot(2k-1), whose k2 is pair 2k-1's (COMPP'd two
// groups ago; LOADW(F) below only touches windows, not k's).
#define GROUP(A, B, C, D, E, F, m) do { \
    SB(); \
    LOADW(E, (m));     LOADW(F, (m) + 1); \
    COMPP(C, bq1);     COMPP(D, 0); \
    CHAIN(A, F);       CHAIN(B, A); \
    FEEDBACK(); } while (0)

// Blocks 0..95: banded soft-DTW per extended batch element -> ws[b].
// Block 96: KL + transition-count losses -> ws[96..98]. Runs concurrently.
__global__ __launch_bounds__(256, 1) void sdtw_fused_kernel(
    const float* __restrict__ at,    // [32,512,4]
    const float* __restrict__ mu,    // [32,64]
    const float* __restrict__ lv,    // [32,64]
    const float* __restrict__ ptc,   // [32,1]
    const float* __restrict__ gt,    // [32,512,4]
    float* __restrict__ ws)          // [0..95]=v, [96]=klS, [97]=auxS, [98]=trS
{
  __shared__ float4 sx[TOT];
  __shared__ float4 sy[TOT];
  __shared__ float s_g[32], s_ps[32], s_kl[32];

  const int blk = blockIdx.x;
  const int t   = threadIdx.x;

  if (blk < 96) {
    const float* xs;
    const float* ys;
    if (blk < 32)      { xs = at + (size_t)blk        * SEQ * 4; ys = gt + (size_t)blk * SEQ * 4; }
    else if (blk < 64) { xs = at + (size_t)(blk - 32) * SEQ * 4; ys = xs; }
    else               { xs = gt + (size_t)(blk - 64) * SEQ * 4; ys = xs; }

    for (int i = t; i < LPAD; i += 256) {
      sx[i] = make_float4(0.f, 0.f, 0.f, 0.f);
      sy[i] = make_float4(0.f, 0.f, 0.f, 0.f);
    }
    for (int i = LPAD + SEQ + t; i < TOT; i += 256) {
      sx[i] = make_float4(0.f, 0.f, 0.f, 0.f);
      sy[i] = make_float4(0.f, 0.f, 0.f, 0.f);
    }
    for (int i = t; i < SEQ; i += 256) {
      sx[LPAD + i] = ((const float4*)xs)[i];
      sy[LPAD + i] = ((const float4*)ys)[i];
    }
    __syncthreads();
    if (t >= 64) return;   // single wave runs the wavefront; no more barriers

    const float4* sxp = sx + LPAD;
    const float4* syp = sy + LPAD;
    const float4* pX = sxp + (t - 31);   // pX[m] = x[m+t-31]
    const float4* pY = syp + (32 - t);   // pY[m] = y[m-t+32]

    // seed: diag 0 = (0,0) at lane31 (even diag of pair -1; its slot is 5, k2_5=0)
    float a0 = -C1f * cost4(sxp[0], syp[0]);
    int   n0 = (int)floorf(a0);
    double e00 = (double)EXP2(a0 - (float)n0);
    double dA = 0.0;
    double dB = (t == 31) ? e00 : 0.0;
    int Ktot = -n0;
    int bq0 = 0, bq1 = 0;

    DECLS(0) DECLS(1) DECLS(2) DECLS(3) DECLS(4) DECLS(5)
    k2_5_init:;
    k25 = 0;   // pair -1's even bump (read by CHAIN(0,5) in group 0)
    k15 = 0;

    // prologue: windows for pairs 0..3; P for pairs 0,1 (bumps 0)
    LOADW(0, 0); LOADW(1, 1); LOADW(2, 2); LOADW(3, 3);
    COMPP(0, 0); COMPP(1, 0);

    // steady: 255 groups (pairs 0..509), 3 groups per iteration (6 pairs)
    #pragma unroll 1
    for (int g = 0; g < 85; ++g) {
      const int m = 6 * g;
      GROUP(0, 1, 2, 3, 4, 5, m + 4);
      GROUP(2, 3, 4, 5, 0, 1, m + 6);
      GROUP(4, 5, 0, 1, 2, 3, m + 8);
    }
    // epilogue: pair 510 (slot 0; prev pair 509 in slot 5)
    SB();
    CHAIN(0, 5);
    Ktot += bq0;   // bump consumed by COMPP(pair 510), landed in the chain above

    if (t == 31) {
      // final cell (511,511) = even diag of pair 510, lane31
      // v = -gamma*ln(E_true) = -K1f*(log2(stored) - Ktot)
      unsigned long long bits = __double_as_longlong(dB);
      int ee = (int)((bits >> 52) & 0x7ffull);
      double mant = __longlong_as_double((bits & 0xFFFFFFFFFFFFFull) | (1023ull << 52));
      double l2 = (double)(ee - 1023) + (double)__log2f((float)mant);
      ws[blk] = (float)(-(double)K1f * (l2 - (double)Ktot));
    }
    return;
  }

  // ---------- loss block (blk == 96), 256 threads: 8 per batch element ----------
  const int b = t >> 3, seg = t & 7;

  float s = 0.f;
  {
    const float* mb = mu + b * 64 + seg * 8;
    const float* lb = lv + b * 64 + seg * 8;
    #pragma unroll
    for (int z = 0; z < 8; ++z) {
      float m = mb[z], l = lb[z];
      s += 1.0f + l - m * m - __expf(l);
    }
  }
  s += __shfl_down(s, 4, 8);
  s += __shfl_down(s, 2, 8);
  s += __shfl_down(s, 1, 8);

  float g = 0.f, ps = 0.f;
  {
    const int n0 = seg * 64;
    const int nstart = (seg == 0) ? 1 : n0;
    const float* gb = gt + (size_t)b * SEQ * 4 + 2;
    const float* ab = at + (size_t)b * SEQ * 4 + 2;
    float pg = gb[(nstart - 1) * 4];
    float pp = 1.0f / (1.0f + __expf((0.5f - ab[(nstart - 1) * 4]) * 10.0f));
    for (int n = nstart; n < n0 + 64; ++n) {
      float cg = gb[n * 4]; g += fabsf(cg - pg); pg = cg;
      float cp = 1.0f / (1.0f + __expf((0.5f - ab[n * 4]) * 10.0f));
      ps += fabsf(cp - pp); pp = cp;
    }
  }
  g  += __shfl_down(g, 4, 8);  g  += __shfl_down(g, 2, 8);  g  += __shfl_down(g, 1, 8);
  ps += __shfl_down(ps, 4, 8); ps += __shfl_down(ps, 2, 8); ps += __shfl_down(ps, 1, 8);

  if (seg == 0) {
    s_g[b]  = g;
    s_ps[b] = ps;
    s_kl[b] = fmaxf(-0.5f * s - 0.5f, 0.0f);
  }
  __syncthreads();

  if (t < 32) {
    float gv  = s_g[t];
    float kl  = s_kl[t];
    float d   = ptc[t] - gv;  float aux = d * d;
    float e   = s_ps[t] - gv; float tr  = e * e;
    kl  += __shfl_down(kl, 16, 32); aux += __shfl_down(aux, 16, 32); tr += __shfl_down(tr, 16, 32);
    kl  += __shfl_down(kl,  8, 32); aux += __shfl_down(aux,  8, 32); tr += __shfl_down(tr,  8, 32);
    kl  += __shfl_down(kl,  4, 32); aux += __shfl_down(aux,  4, 32); tr += __shfl_down(tr,  4, 32);
    kl  += __shfl_down(kl,  2, 32); aux += __shfl_down(aux,  2, 32); tr += __shfl_down(tr,  2, 32);
    kl  += __shfl_down(kl,  1, 32); aux += __shfl_down(aux,  1, 32); tr += __shfl_down(tr,  1, 32);
    if (t == 0) { ws[96] = kl; ws[97] = aux; ws[98] = tr; }
  }
}

__global__ __launch_bounds__(64) void sdtw_combine_kernel(
    const float* __restrict__ ws, float* __restrict__ out)
{
  const int t = threadIdx.x;
  float vn = 0.f;
  if (t < 32) vn = ws[t] - 0.5f * (ws[32 + t] + ws[64 + t]);
  vn += __shfl_down(vn, 16, 32);
  vn += __shfl_down(vn,  8, 32);
  vn += __shfl_down(vn,  4, 32);
  vn += __shfl_down(vn,  2, 32);
  vn += __shfl_down(vn,  1, 32);
  if (t == 0) {
    float recon = vn * (1.0f / 1024.0f);   // mean(diag(v)) = sum/1024
    float kl    = ws[96] * (1.0f / 32.0f);
    float aux   = ws[97] * (1.0f / 32.0f);
    float tr    = ws[98] * (1.0f / 32.0f);
    out[0] = recon + kl + 0.1f * aux + 0.5f * tr;
    out[1] = recon;
    out[2] = kl;
    out[3] = aux;
    out[4] = tr;
  }
}

extern "C" void kernel_launch(void* const* d_in, const int* in_sizes, int n_in,
                              void* d_out, int out_size, void* d_ws, size_t ws_size,
                              hipStream_t stream) {
  const float* at  = (const float*)d_in[0];
  const float* mu  = (const float*)d_in[1];
  const float* lv  = (const float*)d_in[2];
  const float* ptc = (const float*)d_in[3];
  const float* gt  = (const float*)d_in[4];
  float* ws  = (float*)d_ws;
  float* out = (float*)d_out;

  sdtw_fused_kernel<<<97, 256, 0, stream>>>(at, mu, lv, ptc, gt, ws);
  sdtw_combine_kernel<<<1, 64, 0, stream>>>(ws, out);
}